// Round 4
// baseline (540.884 us; speedup 1.0000x reference)
//
#include <hip/hip_runtime.h>
#include <hip/hip_bf16.h>

// Problem constants: B=32, T=1024, D=512, K=3, L=max_len=4096.
#define BB 32
#define TT 1024
#define DD 512
#define LL 4096
#define KDIM 1536        // K*D (im2col reduction dim)
#define TP 1026          // padded T (+1 zero halo row each side)

typedef __attribute__((ext_vector_type(8))) short short8;
typedef __attribute__((ext_vector_type(8))) unsigned short ushort8;
typedef __attribute__((ext_vector_type(4))) float floatx4;

__device__ __forceinline__ unsigned short f2bf(float f) {
  unsigned int u = __builtin_bit_cast(unsigned int, f);
  u += 0x7FFF + ((u >> 16) & 1);
  return (unsigned short)(u >> 16);
}

#define GLOAD_LDS16(g, l)                                          \
  __builtin_amdgcn_global_load_lds(                                \
      (const __attribute__((address_space(1))) void*)(g),          \
      (__attribute__((address_space(3))) void*)(l), 16, 0, 0)

// ---------------------------------------------------------------------------
// enc fp32 -> bf16 padded [32][1026][512] (zero halos), PLUS zeroing the halo
// rows of h1_pad (blocks >= PAD_BLKS).
// ---------------------------------------------------------------------------
#define PAD_BLKS ((BB * TP) / 4)  // 8208
__global__ __launch_bounds__(256) void pad_convert_kernel(
    const float* __restrict__ X, unsigned short* __restrict__ Xp,
    unsigned short* __restrict__ Hp) {
  const int lane = threadIdx.x & 63;
  if (blockIdx.x >= PAD_BLKS) {
    // h1_pad halo zeroing: 64 halo rows, 4 per block
    const int hid = (blockIdx.x - PAD_BLKS) * 4 + (threadIdx.x >> 6);
    const int b = hid >> 1;
    const long r = (long)b * TP + ((hid & 1) ? (TP - 1) : 0);
    *reinterpret_cast<ushort8*>(Hp + r * DD + lane * 8) = (ushort8)0;
    return;
  }
  const int row = blockIdx.x * 4 + (threadIdx.x >> 6);
  const int b  = row / TP;
  const int pr = row - b * TP;
  ushort8* o = reinterpret_cast<ushort8*>(Xp + (long)row * DD + lane * 8);
  ushort8 v;
  if (pr == 0 || pr == TP - 1) {
    v = (ushort8)0;
  } else {
    const float* p = X + ((long)(b * TT + pr - 1)) * DD + lane * 8;
    float4 a = *reinterpret_cast<const float4*>(p);
    float4 c = *reinterpret_cast<const float4*>(p + 4);
    v[0] = f2bf(a.x); v[1] = f2bf(a.y); v[2] = f2bf(a.z); v[3] = f2bf(a.w);
    v[4] = f2bf(c.x); v[5] = f2bf(c.y); v[6] = f2bf(c.z); v[7] = f2bf(c.w);
  }
  *o = v;
}

// ---------------------------------------------------------------------------
// Both weights: W fp32 [1536][512] -> Wt bf16 [512][1536], LDS-tiled 64x64
// transpose so both global read and write are coalesced. grid (8, 24, 2).
// ---------------------------------------------------------------------------
__global__ __launch_bounds__(256) void convert_wt_kernel(
    const float* __restrict__ W1, unsigned short* __restrict__ Wt1,
    const float* __restrict__ W2, unsigned short* __restrict__ Wt2) {
  __shared__ float tile[64][65];
  const float* W = (blockIdx.z == 0) ? W1 : W2;
  unsigned short* Wt = (blockIdx.z == 0) ? Wt1 : Wt2;
  const int n0 = blockIdx.x * 64;   // over DD
  const int k0 = blockIdx.y * 64;   // over KDIM
  const int c = threadIdx.x & 63;
  const int r4 = threadIdx.x >> 6;
#pragma unroll
  for (int r = 0; r < 16; ++r) {
    const int kr = r * 4 + r4;
    tile[kr][c] = W[(long)(k0 + kr) * DD + n0 + c];
  }
  __syncthreads();
#pragma unroll
  for (int r = 0; r < 16; ++r) {
    const int nr = r * 4 + r4;
    Wt[(long)(n0 + nr) * KDIM + k0 + c] = f2bf(tile[c][nr]);
  }
}

// ---------------------------------------------------------------------------
// Fused conv(+bias+ReLU)+LayerNorm[+linear] on matrix cores.
// Tile: 128 rows x 512 (ALL) cols, BK=32, 512 thr = 8 waves laid out as
// 2 row-halves x 4 col-waves; each wave: 64 rows x 128 cols = acc[4][8].
// Grid = 256 blocks = exactly 1 block/CU. Single-buffered LDS (45 KB).
// XOR chunk swizzle (chunk ^= row&3) applied on the global side of
// global_load_lds keeps LDS reads bank-conflict-free.
// MODE 0: write bf16 LN result into padded h1 (row t+1).
// MODE 1: write fp32 dpo[m] = dot(LN result, lw) + lb.
// ---------------------------------------------------------------------------
template <int MODE>
__global__ __launch_bounds__(512, 1) void conv_fused_kernel(
    const unsigned short* __restrict__ Xp, const unsigned short* __restrict__ Wt,
    const float* __restrict__ bias, const float* __restrict__ g,
    const float* __restrict__ be, unsigned short* __restrict__ outH,
    const float* __restrict__ lw, const float* __restrict__ lb,
    float* __restrict__ outD) {
  __shared__ unsigned short As[128 * 32];  // 8 KB
  __shared__ unsigned short Bs[512 * 32];  // 32 KB
  __shared__ float redS[4][128];
  __shared__ float redQ[4][128];

  const int tid  = threadIdx.x;
  const int wid  = tid >> 6;     // 0..7
  const int lane = tid & 63;
  const int h    = wid >> 2;     // row half (0,1)
  const int cw   = wid & 3;      // col quarter
  const int m0   = blockIdx.x * 128;

  // staging lane coords
  const int srow   = lane >> 2;
  const int gchunk = (lane & 3) ^ (srow & 3);

  // fragment lane coords
  const int frow    = lane & 15;
  const int quad    = lane >> 4;
  const int rdchunk = quad ^ (frow & 3);

  // A staging: wave wid stages rows [wid*16, wid*16+16)
  const int mA = m0 + wid * 16 + srow;
  const int bA = mA >> 10;
  const int tA = mA & (TT - 1);
  const unsigned short* gA0 =
      Xp + (long)(bA * TP + tA) * DD + gchunk * 8;  // + tap*DD + c0 per iter
  // B staging: wave wid stages rows wid*16 + 128*q, q=0..3
  const unsigned short* gB0 = Wt + (long)(wid * 16 + srow) * KDIM + gchunk * 8;

  floatx4 acc[4][8];
#pragma unroll
  for (int i = 0; i < 4; ++i)
#pragma unroll
    for (int j = 0; j < 8; ++j) acc[i][j] = (floatx4){0.f, 0.f, 0.f, 0.f};

  for (int k0 = 0; k0 < KDIM; k0 += 32) {
    const int tap = k0 >> 9;
    const int c0  = k0 & 511;
    GLOAD_LDS16(gA0 + (long)tap * DD + c0, &As[(wid * 16) * 32]);
#pragma unroll
    for (int q = 0; q < 4; ++q)
      GLOAD_LDS16(gB0 + (long)q * 128 * KDIM + k0,
                  &Bs[(wid * 16 + q * 128) * 32]);
    __syncthreads();

    short8 af[4], bfr[8];
#pragma unroll
    for (int i = 0; i < 4; ++i)
      af[i] = *reinterpret_cast<const short8*>(
          &As[(h * 64 + i * 16 + frow) * 32 + rdchunk * 8]);
#pragma unroll
    for (int j = 0; j < 8; ++j)
      bfr[j] = *reinterpret_cast<const short8*>(
          &Bs[(cw * 128 + j * 16 + frow) * 32 + rdchunk * 8]);
#pragma unroll
    for (int i = 0; i < 4; ++i)
#pragma unroll
      for (int j = 0; j < 8; ++j)
        acc[i][j] = __builtin_amdgcn_mfma_f32_16x16x32_bf16(
            af[i], bfr[j], acc[i][j], 0, 0, 0);
    __syncthreads();
  }

  // ---- fused epilogue ----
  // lane rows: h*64 + i*16 + quad*4 + r; lane cols: cw*128 + j*16 + frow
  float bz[8], gv[8], bv[8];
#pragma unroll
  for (int j = 0; j < 8; ++j) {
    const int c = cw * 128 + j * 16 + frow;
    bz[j] = bias[c]; gv[j] = g[c]; bv[j] = be[c];
  }
  float ps[16], pq[16];
#pragma unroll
  for (int i = 0; i < 4; ++i)
#pragma unroll
    for (int r = 0; r < 4; ++r) {
      float s = 0.f, q = 0.f;
#pragma unroll
      for (int j = 0; j < 8; ++j) {
        float v = fmaxf(acc[i][j][r] + bz[j], 0.f);
        acc[i][j][r] = v;
        s += v; q += v * v;
      }
      ps[i * 4 + r] = s; pq[i * 4 + r] = q;
    }
#pragma unroll
  for (int off = 1; off < 16; off <<= 1)
#pragma unroll
    for (int k = 0; k < 16; ++k) {
      ps[k] += __shfl_xor(ps[k], off);
      pq[k] += __shfl_xor(pq[k], off);
    }
  if (frow == 0) {
#pragma unroll
    for (int i = 0; i < 4; ++i)
#pragma unroll
      for (int r = 0; r < 4; ++r) {
        const int row = h * 64 + i * 16 + quad * 4 + r;
        redS[cw][row] = ps[i * 4 + r];
        redQ[cw][row] = pq[i * 4 + r];
      }
  }
  __syncthreads();
  float mean[16], rsd[16];
#pragma unroll
  for (int i = 0; i < 4; ++i)
#pragma unroll
    for (int r = 0; r < 4; ++r) {
      const int row = h * 64 + i * 16 + quad * 4 + r;
      const float s = redS[0][row] + redS[1][row] + redS[2][row] + redS[3][row];
      const float q = redQ[0][row] + redQ[1][row] + redQ[2][row] + redQ[3][row];
      const float mu  = s * (1.f / DD);
      const float var = q * (1.f / DD) - mu * mu;
      mean[i * 4 + r] = mu;
      rsd[i * 4 + r]  = rsqrtf(var + 1e-5f);
    }

  if (MODE == 0) {
#pragma unroll
    for (int i = 0; i < 4; ++i)
#pragma unroll
      for (int r = 0; r < 4; ++r) {
        const int m = m0 + h * 64 + i * 16 + quad * 4 + r;
        const int b = m >> 10, t = m & (TT - 1);
        unsigned short* dst = outH + (long)(b * TP + t + 1) * DD;
        const float mu = mean[i * 4 + r], rs = rsd[i * 4 + r];
#pragma unroll
        for (int j = 0; j < 8; ++j)
          dst[cw * 128 + j * 16 + frow] =
              f2bf((acc[i][j][r] - mu) * rs * gv[j] + bv[j]);
      }
  } else {
    float lwv[8];
#pragma unroll
    for (int j = 0; j < 8; ++j) lwv[j] = lw[cw * 128 + j * 16 + frow];
    float pd[16];
#pragma unroll
    for (int i = 0; i < 4; ++i)
#pragma unroll
      for (int r = 0; r < 4; ++r) {
        const float mu = mean[i * 4 + r], rs = rsd[i * 4 + r];
        float d = 0.f;
#pragma unroll
        for (int j = 0; j < 8; ++j)
          d += ((acc[i][j][r] - mu) * rs * gv[j] + bv[j]) * lwv[j];
        pd[i * 4 + r] = d;
      }
#pragma unroll
    for (int off = 1; off < 16; off <<= 1)
#pragma unroll
      for (int k = 0; k < 16; ++k) pd[k] += __shfl_xor(pd[k], off);
    __syncthreads();  // done reading redS/redQ above
    if (frow == 0) {
#pragma unroll
      for (int i = 0; i < 4; ++i)
#pragma unroll
        for (int r = 0; r < 4; ++r)
          redS[cw][h * 64 + i * 16 + quad * 4 + r] = pd[i * 4 + r];
    }
    __syncthreads();
    if (cw == 0 && frow == 0) {
#pragma unroll
      for (int i = 0; i < 4; ++i)
#pragma unroll
        for (int r = 0; r < 4; ++r) {
          const int row = h * 64 + i * 16 + quad * 4 + r;
          outD[m0 + row] = redS[0][row] + redS[1][row] + redS[2][row] +
                           redS[3][row] + lb[0];
        }
    }
  }
}

// Inclusive cumsum over T=1024 per batch.
__global__ __launch_bounds__(1024) void cumsum_kernel(
    const int* __restrict__ dur, int* __restrict__ cum) {
  __shared__ int s[TT];
  const int b = blockIdx.x, t = threadIdx.x;
  s[t] = dur[b * TT + t];
  __syncthreads();
  for (int off = 1; off < TT; off <<= 1) {
    int x = (t >= off) ? s[t - off] : 0;
    __syncthreads();
    s[t] += x;
    __syncthreads();
  }
  cum[b * TT + t] = s[t];
}

// Gather/expand: one 128-thread block per output frame [b, j].
__global__ __launch_bounds__(128) void gather_kernel(
    const float* __restrict__ X, const int* __restrict__ cum,
    float* __restrict__ out) {
  const long blk = blockIdx.x;
  const int b = (int)(blk >> 12);
  const int j = (int)(blk & (LL - 1));
  const int* c = cum + b * TT;
  float4* o = reinterpret_cast<float4*>(out + blk * DD) + threadIdx.x;
  const int total = c[TT - 1];
  if (j >= total) {
    *o = make_float4(0.f, 0.f, 0.f, 0.f);
    return;
  }
  int lo = 0, hi = TT - 1;
  while (lo < hi) {
    const int mid = (lo + hi) >> 1;
    if (c[mid] <= j) lo = mid + 1; else hi = mid;
  }
  const float4* src =
      reinterpret_cast<const float4*>(X + ((long)b * TT + lo) * DD) +
      threadIdx.x;
  *o = *src;
}

// ---------------------------------------------------------------------------
extern "C" void kernel_launch(void* const* d_in, const int* in_sizes, int n_in,
                              void* d_out, int out_size, void* d_ws,
                              size_t ws_size, hipStream_t stream) {
  const float* enc = (const float*)d_in[0];
  const int* dur   = (const int*)d_in[1];
  const float* w1  = (const float*)d_in[2];
  const float* b1  = (const float*)d_in[3];
  const float* g1  = (const float*)d_in[4];
  const float* be1 = (const float*)d_in[5];
  const float* w2  = (const float*)d_in[6];
  const float* b2  = (const float*)d_in[7];
  const float* g2  = (const float*)d_in[8];
  const float* be2 = (const float*)d_in[9];
  const float* lw  = (const float*)d_in[10];
  const float* lb  = (const float*)d_in[11];

  float* out = (float*)d_out;
  float* expanded = out;                       // [B, L, D] = 67,108,864 f
  float* dpo = out + (long)BB * LL * DD;       // [B, T]

  // Scratch carved out of the expanded region (gather writes it last).
  unsigned short* enc_pad = (unsigned short*)(expanded);             // 33.6 MB
  unsigned short* h1_pad  = (unsigned short*)(expanded + 9000000);   // 33.6 MB
  unsigned short* wt1     = (unsigned short*)(expanded + 18000000);  // 1.5 MB
  unsigned short* wt2     = (unsigned short*)(expanded + 18500000);  // 1.5 MB
  int* cum = (int*)d_ws;

  const int rows = BB * TT;  // 32768

  pad_convert_kernel<<<PAD_BLKS + 16, 256, 0, stream>>>(enc, enc_pad, h1_pad);
  convert_wt_kernel<<<dim3(DD / 64, KDIM / 64, 2), 256, 0, stream>>>(
      w1, wt1, w2, wt2);

  conv_fused_kernel<0><<<rows / 128, 512, 0, stream>>>(
      enc_pad, wt1, b1, g1, be1, h1_pad, nullptr, nullptr, nullptr);
  conv_fused_kernel<1><<<rows / 128, 512, 0, stream>>>(
      h1_pad, wt2, b2, g2, be2, nullptr, lw, lb, dpo);

  cumsum_kernel<<<BB, 1024, 0, stream>>>(dur, cum);
  gather_kernel<<<BB * LL, 128, 0, stream>>>(enc, cum, expanded);
}

// Round 5
// 535.245 us; speedup vs baseline: 1.0105x; 1.0105x over previous
//
#include <hip/hip_runtime.h>
#include <hip/hip_bf16.h>

// Problem constants: B=32, T=1024, D=512, K=3, L=max_len=4096.
#define BB 32
#define TT 1024
#define DD 512
#define LL 4096
#define KDIM 1536        // K*D (im2col reduction dim)
#define TP 1026          // padded T (+1 zero halo row each side)
#define ROWS (BB * TT)   // 32768

typedef __attribute__((ext_vector_type(8))) short short8;
typedef __attribute__((ext_vector_type(8))) unsigned short ushort8;
typedef __attribute__((ext_vector_type(4))) float floatx4;

__device__ __forceinline__ unsigned short f2bf(float f) {
  unsigned int u = __builtin_bit_cast(unsigned int, f);
  u += 0x7FFF + ((u >> 16) & 1);
  return (unsigned short)(u >> 16);
}
__device__ __forceinline__ float bf2f(unsigned short h) {
  return __builtin_bit_cast(float, (unsigned int)h << 16);
}

#define GLOAD_LDS16(g, l)                                          \
  __builtin_amdgcn_global_load_lds(                                \
      (const __attribute__((address_space(1))) void*)(g),          \
      (__attribute__((address_space(3))) void*)(l), 16, 0, 0)

// ---------------------------------------------------------------------------
// enc fp32 -> bf16 padded [32][1026][512] (zero halos), PLUS zeroing the halo
// rows of h1_pad (blocks >= PAD_BLKS).
// ---------------------------------------------------------------------------
#define PAD_BLKS ((BB * TP) / 4)  // 8208
__global__ __launch_bounds__(256) void pad_convert_kernel(
    const float* __restrict__ X, unsigned short* __restrict__ Xp,
    unsigned short* __restrict__ Hp) {
  const int lane = threadIdx.x & 63;
  if (blockIdx.x >= PAD_BLKS) {
    const int hid = (blockIdx.x - PAD_BLKS) * 4 + (threadIdx.x >> 6);
    const int b = hid >> 1;
    const long r = (long)b * TP + ((hid & 1) ? (TP - 1) : 0);
    *reinterpret_cast<ushort8*>(Hp + r * DD + lane * 8) = (ushort8)0;
    return;
  }
  const int row = blockIdx.x * 4 + (threadIdx.x >> 6);
  const int b  = row / TP;
  const int pr = row - b * TP;
  ushort8* o = reinterpret_cast<ushort8*>(Xp + (long)row * DD + lane * 8);
  ushort8 v;
  if (pr == 0 || pr == TP - 1) {
    v = (ushort8)0;
  } else {
    const float* p = X + ((long)(b * TT + pr - 1)) * DD + lane * 8;
    float4 a = *reinterpret_cast<const float4*>(p);
    float4 c = *reinterpret_cast<const float4*>(p + 4);
    v[0] = f2bf(a.x); v[1] = f2bf(a.y); v[2] = f2bf(a.z); v[3] = f2bf(a.w);
    v[4] = f2bf(c.x); v[5] = f2bf(c.y); v[6] = f2bf(c.z); v[7] = f2bf(c.w);
  }
  *o = v;
}

// ---------------------------------------------------------------------------
// Both weights: W fp32 [1536][512] -> Wt bf16 [512][1536], LDS-tiled.
// ---------------------------------------------------------------------------
__global__ __launch_bounds__(256) void convert_wt_kernel(
    const float* __restrict__ W1, unsigned short* __restrict__ Wt1,
    const float* __restrict__ W2, unsigned short* __restrict__ Wt2) {
  __shared__ float tile[64][65];
  const float* W = (blockIdx.z == 0) ? W1 : W2;
  unsigned short* Wt = (blockIdx.z == 0) ? Wt1 : Wt2;
  const int n0 = blockIdx.x * 64;
  const int k0 = blockIdx.y * 64;
  const int c = threadIdx.x & 63;
  const int r4 = threadIdx.x >> 6;
#pragma unroll
  for (int r = 0; r < 16; ++r) tile[r * 4 + r4][c] = W[(long)(k0 + r * 4 + r4) * DD + n0 + c];
  __syncthreads();
#pragma unroll
  for (int r = 0; r < 16; ++r)
    Wt[(long)(n0 + r * 4 + r4) * KDIM + k0 + c] = f2bf(tile[c][r * 4 + r4]);
}

// ---------------------------------------------------------------------------
// Conv-as-GEMM, m97 geometry: 128x128 tile, BK=32, 256 thr = 4 waves (2x2 of
// 64x64, acc[4][4]). __launch_bounds__(256,3) caps VGPR (~170) -> 3 blocks/CU
// so independent blocks hide each other's barrier/vmcnt drains (m114).
// Epilogue: relu(acc+bias) -> bf16 Y, plus per-(colblock,row) partial
// sum/sumsq written to Ps/Pq[by*ROWS + m] (unique writer, no atomics).
// XOR chunk swizzle on the global side keeps LDS reads conflict-free.
// ---------------------------------------------------------------------------
__global__ __launch_bounds__(256, 3) void conv_gemm_kernel(
    const unsigned short* __restrict__ Xp, const unsigned short* __restrict__ Wt,
    const float* __restrict__ bias, unsigned short* __restrict__ Ybf,
    float* __restrict__ Ps, float* __restrict__ Pq) {
  __shared__ unsigned short As[128 * 32];  // 8 KB
  __shared__ unsigned short Bs[128 * 32];  // 8 KB
  __shared__ float redS[2][128];
  __shared__ float redQ[2][128];

  const int tid  = threadIdx.x;
  const int wid  = tid >> 6;
  const int lane = tid & 63;
  const int m0   = blockIdx.x * 128;
  const int n0   = blockIdx.y * 128;
  const int wm   = (wid >> 1) * 64;
  const int wn   = (wid & 1) * 64;

  const int srow   = lane >> 2;
  const int gchunk = (lane & 3) ^ (srow & 3);
  const int frow   = lane & 15;
  const int quad   = lane >> 4;
  const int rdchunk = quad ^ (frow & 3);

  // A: 128-row tiles never cross a batch (1024 % 128 == 0).
  const int bA = m0 >> 10;
  const int t0 = m0 & (TT - 1);
  const unsigned short* gA0 =
      Xp + (long)(bA * TP + t0 + wid * 16 + srow) * DD + gchunk * 8;
  const unsigned short* gB0 =
      Wt + (long)(n0 + wid * 16 + srow) * KDIM + gchunk * 8;

  floatx4 acc[4][4];
#pragma unroll
  for (int i = 0; i < 4; ++i)
#pragma unroll
    for (int j = 0; j < 4; ++j) acc[i][j] = (floatx4){0.f, 0.f, 0.f, 0.f};

  for (int k0 = 0; k0 < KDIM; k0 += 32) {
    const int tap = k0 >> 9;
    const int c0  = k0 & 511;
    const unsigned short* gA = gA0 + (long)tap * DD + c0;
    GLOAD_LDS16(gA, &As[(wid * 16) * 32]);
    GLOAD_LDS16(gA + (long)64 * DD, &As[(64 + wid * 16) * 32]);
    GLOAD_LDS16(gB0 + k0, &Bs[(wid * 16) * 32]);
    GLOAD_LDS16(gB0 + (long)64 * KDIM + k0, &Bs[(64 + wid * 16) * 32]);
    __syncthreads();

    short8 af[4], bf[4];
#pragma unroll
    for (int i = 0; i < 4; ++i)
      af[i] = *reinterpret_cast<const short8*>(
          &As[(wm + i * 16 + frow) * 32 + rdchunk * 8]);
#pragma unroll
    for (int j = 0; j < 4; ++j)
      bf[j] = *reinterpret_cast<const short8*>(
          &Bs[(wn + j * 16 + frow) * 32 + rdchunk * 8]);
#pragma unroll
    for (int i = 0; i < 4; ++i)
#pragma unroll
      for (int j = 0; j < 4; ++j)
        acc[i][j] = __builtin_amdgcn_mfma_f32_16x16x32_bf16(
            af[i], bf[j], acc[i][j], 0, 0, 0);
    __syncthreads();
  }

  // Epilogue: bias+relu, bf16 Y store, partial LN stats for this col-block.
  float bz[4];
#pragma unroll
  for (int j = 0; j < 4; ++j) bz[j] = bias[n0 + wn + j * 16 + frow];
  float ps[16], pq[16];
#pragma unroll
  for (int i = 0; i < 4; ++i)
#pragma unroll
    for (int r = 0; r < 4; ++r) {
      const long m = m0 + wm + i * 16 + quad * 4 + r;
      float s = 0.f, q = 0.f;
#pragma unroll
      for (int j = 0; j < 4; ++j) {
        const float v = fmaxf(acc[i][j][r] + bz[j], 0.f);
        Ybf[m * DD + n0 + wn + j * 16 + frow] = f2bf(v);
        s += v; q += v * v;
      }
      ps[i * 4 + r] = s; pq[i * 4 + r] = q;
    }
#pragma unroll
  for (int off = 1; off < 16; off <<= 1)
#pragma unroll
    for (int k = 0; k < 16; ++k) {
      ps[k] += __shfl_xor(ps[k], off);
      pq[k] += __shfl_xor(pq[k], off);
    }
  if (frow == 0) {
#pragma unroll
    for (int i = 0; i < 4; ++i)
#pragma unroll
      for (int r = 0; r < 4; ++r) {
        const int row = wm + i * 16 + quad * 4 + r;
        redS[wn >> 6][row] = ps[i * 4 + r];
        redQ[wn >> 6][row] = pq[i * 4 + r];
      }
  }
  __syncthreads();
  if (wn == 0 && frow == 0) {
    const long pb = (long)blockIdx.y * ROWS + m0;
#pragma unroll
    for (int i = 0; i < 4; ++i)
#pragma unroll
      for (int r = 0; r < 4; ++r) {
        const int row = wm + i * 16 + quad * 4 + r;
        Ps[pb + row] = redS[0][row] + redS[1][row];
        Pq[pb + row] = redQ[0][row] + redQ[1][row];
      }
  }
}

// ---------------------------------------------------------------------------
// LN apply #1: read bf16 Y + partial stats, write bf16 h1_pad (row t+1).
// ---------------------------------------------------------------------------
__global__ __launch_bounds__(256) void ln_apply1_kernel(
    const unsigned short* __restrict__ Ybf, const float* __restrict__ Ps,
    const float* __restrict__ Pq, const float* __restrict__ g,
    const float* __restrict__ be, unsigned short* __restrict__ Hp) {
  const int row  = blockIdx.x * 4 + (threadIdx.x >> 6);
  const int lane = threadIdx.x & 63;
  const float s = Ps[row] + Ps[ROWS + row] + Ps[2 * ROWS + row] + Ps[3 * ROWS + row];
  const float q = Pq[row] + Pq[ROWS + row] + Pq[2 * ROWS + row] + Pq[3 * ROWS + row];
  const float mu = s * (1.f / DD);
  const float var = q * (1.f / DD) - mu * mu;
  const float rs = rsqrtf(var + 1e-5f);
  ushort8 y = *reinterpret_cast<const ushort8*>(Ybf + (long)row * DD + lane * 8);
  float4 g0 = *reinterpret_cast<const float4*>(g + lane * 8);
  float4 g1 = *reinterpret_cast<const float4*>(g + lane * 8 + 4);
  float4 b0 = *reinterpret_cast<const float4*>(be + lane * 8);
  float4 b1 = *reinterpret_cast<const float4*>(be + lane * 8 + 4);
  ushort8 o;
  o[0] = f2bf((bf2f(y[0]) - mu) * rs * g0.x + b0.x);
  o[1] = f2bf((bf2f(y[1]) - mu) * rs * g0.y + b0.y);
  o[2] = f2bf((bf2f(y[2]) - mu) * rs * g0.z + b0.z);
  o[3] = f2bf((bf2f(y[3]) - mu) * rs * g0.w + b0.w);
  o[4] = f2bf((bf2f(y[4]) - mu) * rs * g1.x + b1.x);
  o[5] = f2bf((bf2f(y[5]) - mu) * rs * g1.y + b1.y);
  o[6] = f2bf((bf2f(y[6]) - mu) * rs * g1.z + b1.z);
  o[7] = f2bf((bf2f(y[7]) - mu) * rs * g1.w + b1.w);
  const int b = row >> 10, t = row & (TT - 1);
  *reinterpret_cast<ushort8*>(Hp + (long)(b * TP + t + 1) * DD + lane * 8) = o;
}

// ---------------------------------------------------------------------------
// LN apply #2 + linear: dpo[row] = dot(LN(Y2[row]), lw) + lb.
// ---------------------------------------------------------------------------
__global__ __launch_bounds__(256) void ln_apply2_kernel(
    const unsigned short* __restrict__ Ybf, const float* __restrict__ Ps,
    const float* __restrict__ Pq, const float* __restrict__ g,
    const float* __restrict__ be, const float* __restrict__ lw,
    const float* __restrict__ lb, float* __restrict__ outD) {
  const int row  = blockIdx.x * 4 + (threadIdx.x >> 6);
  const int lane = threadIdx.x & 63;
  const float s = Ps[row] + Ps[ROWS + row] + Ps[2 * ROWS + row] + Ps[3 * ROWS + row];
  const float q = Pq[row] + Pq[ROWS + row] + Pq[2 * ROWS + row] + Pq[3 * ROWS + row];
  const float mu = s * (1.f / DD);
  const float var = q * (1.f / DD) - mu * mu;
  const float rs = rsqrtf(var + 1e-5f);
  ushort8 y = *reinterpret_cast<const ushort8*>(Ybf + (long)row * DD + lane * 8);
  float4 g0 = *reinterpret_cast<const float4*>(g + lane * 8);
  float4 g1 = *reinterpret_cast<const float4*>(g + lane * 8 + 4);
  float4 b0 = *reinterpret_cast<const float4*>(be + lane * 8);
  float4 b1 = *reinterpret_cast<const float4*>(be + lane * 8 + 4);
  float4 w0 = *reinterpret_cast<const float4*>(lw + lane * 8);
  float4 w1 = *reinterpret_cast<const float4*>(lw + lane * 8 + 4);
  float d = ((bf2f(y[0]) - mu) * rs * g0.x + b0.x) * w0.x +
            ((bf2f(y[1]) - mu) * rs * g0.y + b0.y) * w0.y +
            ((bf2f(y[2]) - mu) * rs * g0.z + b0.z) * w0.z +
            ((bf2f(y[3]) - mu) * rs * g0.w + b0.w) * w0.w +
            ((bf2f(y[4]) - mu) * rs * g1.x + b1.x) * w1.x +
            ((bf2f(y[5]) - mu) * rs * g1.y + b1.y) * w1.y +
            ((bf2f(y[6]) - mu) * rs * g1.z + b1.z) * w1.z +
            ((bf2f(y[7]) - mu) * rs * g1.w + b1.w) * w1.w;
#pragma unroll
  for (int off = 32; off > 0; off >>= 1) d += __shfl_xor(d, off);
  if (lane == 0) outD[row] = d + lb[0];
}

// Inclusive cumsum over T=1024 per batch.
__global__ __launch_bounds__(1024) void cumsum_kernel(
    const int* __restrict__ dur, int* __restrict__ cum) {
  __shared__ int s[TT];
  const int b = blockIdx.x, t = threadIdx.x;
  s[t] = dur[b * TT + t];
  __syncthreads();
  for (int off = 1; off < TT; off <<= 1) {
    int x = (t >= off) ? s[t - off] : 0;
    __syncthreads();
    s[t] += x;
    __syncthreads();
  }
  cum[b * TT + t] = s[t];
}

// Gather/expand: one 128-thread block per output frame [b, j].
__global__ __launch_bounds__(128) void gather_kernel(
    const float* __restrict__ X, const int* __restrict__ cum,
    float* __restrict__ out) {
  const long blk = blockIdx.x;
  const int b = (int)(blk >> 12);
  const int j = (int)(blk & (LL - 1));
  const int* c = cum + b * TT;
  float4* o = reinterpret_cast<float4*>(out + blk * DD) + threadIdx.x;
  const int total = c[TT - 1];
  if (j >= total) {
    *o = make_float4(0.f, 0.f, 0.f, 0.f);
    return;
  }
  int lo = 0, hi = TT - 1;
  while (lo < hi) {
    const int mid = (lo + hi) >> 1;
    if (c[mid] <= j) lo = mid + 1; else hi = mid;
  }
  const float4* src =
      reinterpret_cast<const float4*>(X + ((long)b * TT + lo) * DD) +
      threadIdx.x;
  *o = *src;
}

// ---------------------------------------------------------------------------
extern "C" void kernel_launch(void* const* d_in, const int* in_sizes, int n_in,
                              void* d_out, int out_size, void* d_ws,
                              size_t ws_size, hipStream_t stream) {
  const float* enc = (const float*)d_in[0];
  const int* dur   = (const int*)d_in[1];
  const float* w1  = (const float*)d_in[2];
  const float* b1  = (const float*)d_in[3];
  const float* g1  = (const float*)d_in[4];
  const float* be1 = (const float*)d_in[5];
  const float* w2  = (const float*)d_in[6];
  const float* b2  = (const float*)d_in[7];
  const float* g2  = (const float*)d_in[8];
  const float* be2 = (const float*)d_in[9];
  const float* lw  = (const float*)d_in[10];
  const float* lb  = (const float*)d_in[11];

  float* out = (float*)d_out;
  float* expanded = out;                       // [B, L, D] = 67,108,864 f
  float* dpo = out + (long)BB * LL * DD;       // [B, T]

  // Scratch carved out of the 256 MB expanded region (gather writes it last).
  unsigned short* enc_pad = (unsigned short*)(expanded);              // 33.6 MB
  unsigned short* h1_pad  = (unsigned short*)(expanded + 9000000);    // 33.6 MB
  unsigned short* wt1     = (unsigned short*)(expanded + 18000000);   // 1.5 MB
  unsigned short* wt2     = (unsigned short*)(expanded + 18400000);   // 1.5 MB
  unsigned short* ybf1    = (unsigned short*)(expanded + 19000000);   // 33.6 MB
  unsigned short* ybf2    = (unsigned short*)(expanded + 27400000);   // 33.6 MB
  float* p1s = expanded + 36000000;   // 4*ROWS = 131072 f each
  float* p1q = expanded + 36200000;
  float* p2s = expanded + 36400000;
  float* p2q = expanded + 36600000;
  int* cum = (int*)d_ws;

  pad_convert_kernel<<<PAD_BLKS + 16, 256, 0, stream>>>(enc, enc_pad, h1_pad);
  convert_wt_kernel<<<dim3(DD / 64, KDIM / 64, 2), 256, 0, stream>>>(
      w1, wt1, w2, wt2);

  dim3 gemm_grid(ROWS / 128, DD / 128);  // (256, 4)
  conv_gemm_kernel<<<gemm_grid, 256, 0, stream>>>(enc_pad, wt1, b1, ybf1,
                                                  p1s, p1q);
  ln_apply1_kernel<<<ROWS / 4, 256, 0, stream>>>(ybf1, p1s, p1q, g1, be1,
                                                 h1_pad);
  conv_gemm_kernel<<<gemm_grid, 256, 0, stream>>>(h1_pad, wt2, b2, ybf2,
                                                  p2s, p2q);
  ln_apply2_kernel<<<ROWS / 4, 256, 0, stream>>>(ybf2, p2s, p2q, g2, be2,
                                                 lw, lb, dpo);

  cumsum_kernel<<<BB, 1024, 0, stream>>>(dur, cum);
  gather_kernel<<<BB * LL, 128, 0, stream>>>(enc, cum, expanded);
}